// Round 7
// baseline (168.485 us; speedup 1.0000x reference)
//
#include <hip/hip_runtime.h>

typedef unsigned short u16;
typedef __attribute__((ext_vector_type(8))) __bf16 bf16x8;
typedef __attribute__((ext_vector_type(4))) float f32x4;

struct alignas(8) U16x4 { u16 x, y, z, w; };

#define MFMA16(a, b, c) __builtin_amdgcn_mfma_f32_16x16x32_bf16(a, b, c, 0, 0, 0)

__device__ __forceinline__ u16 f2bf(float f) {
    union { float f; unsigned u; } v; v.f = f;
    unsigned r = v.u + 0x7fffu + ((v.u >> 16) & 1u);
    return (u16)(r >> 16);
}

__device__ __forceinline__ unsigned cvt_pk_bf16(float lo, float hi) {
    unsigned r;
    asm("v_cvt_pk_bf16_f32 %0, %1, %2" : "=v"(r) : "v"(lo), "v"(hi));
    return r;
}

__device__ __forceinline__ float fexp2(float x) {   // raw v_exp_f32 (2^x)
    float r;
    asm("v_exp_f32 %0, %1" : "=v"(r) : "v"(x));
    return r;
}

__device__ __forceinline__ void gload_lds16(const void* g, void* l) {
    __builtin_amdgcn_global_load_lds(
        (__attribute__((address_space(1))) void*)g,
        (__attribute__((address_space(3))) void*)l, 16, 0, 0);
}

// ---------------------------------------------------------------------------
// prep: fused LN(query)+LN(context)+weight-conversion (unchanged).
// ---------------------------------------------------------------------------
__global__ __launch_bounds__(256)
void prep(const float* __restrict__ query, const float* __restrict__ context,
          const float* __restrict__ g_q, const float* __restrict__ b_q,
          const float* __restrict__ g_kv, const float* __restrict__ b_kv,
          float* __restrict__ qn32, u16* __restrict__ qnb, u16* __restrict__ cnb,
          const float4* __restrict__ w0, const float4* __restrict__ w1,
          const float4* __restrict__ w2, const float4* __restrict__ w3,
          U16x4* __restrict__ o0, U16x4* __restrict__ o1,
          U16x4* __restrict__ o2, U16x4* __restrict__ o3)
{
    const int blk = blockIdx.x;
    if (blk < 2560) {
        const float *x, *g, *be; float* y32; u16* y16; int rb;
        if (blk < 512) { x = query;   g = g_q;  be = b_q;  y32 = qn32;    y16 = qnb; rb = blk; }
        else           { x = context; g = g_kv; be = b_kv; y32 = nullptr; y16 = cnb; rb = blk - 512; }
        const int wid = threadIdx.x >> 6, lane = threadIdx.x & 63;
        const size_t row = (size_t)rb * 4 + wid;
        const float4* xr = (const float4*)(x + row * 1024);
        float4 v[4];
        float s = 0.f, ss = 0.f;
#pragma unroll
        for (int i = 0; i < 4; ++i) {
            v[i] = xr[i * 64 + lane];
            s  += (v[i].x + v[i].y) + (v[i].z + v[i].w);
            ss += (v[i].x * v[i].x + v[i].y * v[i].y) + (v[i].z * v[i].z + v[i].w * v[i].w);
        }
#pragma unroll
        for (int o = 32; o; o >>= 1) { s += __shfl_xor(s, o, 64); ss += __shfl_xor(ss, o, 64); }
        const float mu = s * (1.f / 1024.f);
        const float rstd = rsqrtf(ss * (1.f / 1024.f) - mu * mu + 1e-5f);
#pragma unroll
        for (int i = 0; i < 4; ++i) {
            float4 gv = ((const float4*)g)[i * 64 + lane];
            float4 bv = ((const float4*)be)[i * 64 + lane];
            float4 o;
            o.x = (v[i].x - mu) * rstd * gv.x + bv.x;
            o.y = (v[i].y - mu) * rstd * gv.y + bv.y;
            o.z = (v[i].z - mu) * rstd * gv.z + bv.z;
            o.w = (v[i].w - mu) * rstd * gv.w + bv.w;
            if (y32) ((float4*)(y32 + row * 1024))[i * 64 + lane] = o;
            U16x4 pk = { f2bf(o.x), f2bf(o.y), f2bf(o.z), f2bf(o.w) };
            ((U16x4*)(y16 + row * 1024))[i * 64 + lane] = pk;
        }
    } else {
        const int i = (blk - 2560) * 256 + threadIdx.x;
        float4 v;
        v = w0[i]; o0[i] = { f2bf(v.x), f2bf(v.y), f2bf(v.z), f2bf(v.w) };
        v = w1[i]; o1[i] = { f2bf(v.x), f2bf(v.y), f2bf(v.z), f2bf(v.w) };
        v = w2[i]; o2[i] = { f2bf(v.x), f2bf(v.y), f2bf(v.z), f2bf(v.w) };
        v = w3[i]; o3[i] = { f2bf(v.x), f2bf(v.y), f2bf(v.z), f2bf(v.w) };
    }
}

// ---------------------------------------------------------------------------
// Merged K+V projection GEMM (unchanged).
// ---------------------------------------------------------------------------
__global__ __launch_bounds__(512, 4)
void gemm_kv(const u16* __restrict__ A, const u16* __restrict__ Wk,
             const u16* __restrict__ Wv, const float* __restrict__ bkp,
             const float* __restrict__ bvp, u16* __restrict__ Kout,
             u16* __restrict__ Vt)
{
    constexpr int K = 1024, N = 1024, BK = 64;
    __shared__ __align__(16) u16 sA[128 * BK];
    __shared__ __align__(16) u16 sK[128 * BK];
    __shared__ __align__(16) u16 sV[128 * BK];
    const int tid = threadIdx.x, wid = tid >> 6, lane = tid & 63;
    const int lr = lane & 15, lg = lane >> 4;
    const int wr = wid >> 2, wc = wid & 3;
    const int row0 = blockIdx.x * 128, col0 = blockIdx.y * 128;
    const int srow = wid * 8 + (lane >> 3), scol = (lane & 7) * 8;

    const u16* Ag = A  + (size_t)(row0 + srow) * K + scol;
    const u16* Kg = Wk + (size_t)(col0 + srow) * K + scol;
    const u16* Vg = Wv + (size_t)(col0 + srow) * K + scol;

    f32x4 ka[4][2], va[4][2];
#pragma unroll
    for (int m = 0; m < 4; ++m)
#pragma unroll
        for (int n = 0; n < 2; ++n) {
            ka[m][n] = (f32x4){0.f, 0.f, 0.f, 0.f};
            va[m][n] = (f32x4){0.f, 0.f, 0.f, 0.f};
        }

    for (int k0 = 0; k0 < K; k0 += BK) {
        __syncthreads();
#pragma unroll
        for (int i = 0; i < 2; ++i) {
            gload_lds16(Ag + (size_t)i * 64 * K + k0, (char*)sA + i * 8192 + wid * 1024);
            gload_lds16(Kg + (size_t)i * 64 * K + k0, (char*)sK + i * 8192 + wid * 1024);
            gload_lds16(Vg + (size_t)i * 64 * K + k0, (char*)sV + i * 8192 + wid * 1024);
        }
        __syncthreads();
#pragma unroll
        for (int kk = 0; kk < 2; ++kk) {
            bf16x8 af[4], bk[2], bv[2];
#pragma unroll
            for (int m = 0; m < 4; ++m)
                af[m] = *(const bf16x8*)&sA[(wr * 64 + m * 16 + lr) * BK + kk * 32 + lg * 8];
#pragma unroll
            for (int n = 0; n < 2; ++n) {
                bk[n] = *(const bf16x8*)&sK[(wc * 32 + n * 16 + lr) * BK + kk * 32 + lg * 8];
                bv[n] = *(const bf16x8*)&sV[(wc * 32 + n * 16 + lr) * BK + kk * 32 + lg * 8];
            }
#pragma unroll
            for (int m = 0; m < 4; ++m)
#pragma unroll
                for (int n = 0; n < 2; ++n) {
                    ka[m][n] = MFMA16(af[m], bk[n], ka[m][n]);
                    va[m][n] = MFMA16(af[m], bv[n], va[m][n]);
                }
        }
    }

#pragma unroll
    for (int m = 0; m < 4; ++m) {
#pragma unroll
        for (int n = 0; n < 2; ++n) {
            const int r = row0 + wr * 64 + m * 16 + lg * 4;
            const int c = col0 + wc * 32 + n * 16 + lr;
            const float kb = bkp[c], vb = bvp[c];
#pragma unroll
            for (int j = 0; j < 4; ++j)
                Kout[(size_t)(r + j) * N + c] = f2bf(ka[m][n][j] + kb);
            const size_t base = ((size_t)(r >> 12) * 1024 + c) * 4096 + (r & 4095);
            U16x4 pk = { f2bf(va[m][n][0] + vb), f2bf(va[m][n][1] + vb),
                         f2bf(va[m][n][2] + vb), f2bf(va[m][n][3] + vb) };
            *(U16x4*)&Vt[base] = pk;
        }
    }
}

// ---------------------------------------------------------------------------
// Q/O projection GEMM, 64x128 tile (unchanged).
// ---------------------------------------------------------------------------
template<int MODE>
__global__ __launch_bounds__(256)
void gemm_bt64(const u16* __restrict__ A, const u16* __restrict__ W,
               const float* __restrict__ bias, const float* __restrict__ resid,
               void* __restrict__ Cp, int M, int N, int K, float alpha)
{
    constexpr int BK = 64;
    __shared__ __align__(16) u16 sA[64 * BK];
    __shared__ __align__(16) u16 sB[128 * BK];
    const int tid = threadIdx.x, wid = tid >> 6, lane = tid & 63;
    const int lr = lane & 15, lg = lane >> 4;
    const int wr = wid >> 1, wc = wid & 1;
    const int row0 = blockIdx.x * 64, col0 = blockIdx.y * 128;
    const int srow = wid * 8 + (lane >> 3), scol = (lane & 7) * 8;

    const u16* Ag = A + (size_t)(row0 + srow) * K + scol;
    const u16* Wg = W + (size_t)(col0 + srow) * K + scol;

    f32x4 acc[2][4];
#pragma unroll
    for (int m = 0; m < 2; ++m)
#pragma unroll
        for (int n = 0; n < 4; ++n) acc[m][n] = (f32x4){0.f, 0.f, 0.f, 0.f};

    for (int k0 = 0; k0 < K; k0 += BK) {
        __syncthreads();
#pragma unroll
        for (int i = 0; i < 2; ++i)
            gload_lds16(Ag + (size_t)i * 32 * K + k0, (char*)sA + i * 4096 + wid * 1024);
#pragma unroll
        for (int i = 0; i < 4; ++i)
            gload_lds16(Wg + (size_t)i * 32 * K + k0, (char*)sB + i * 4096 + wid * 1024);
        __syncthreads();
#pragma unroll
        for (int kk = 0; kk < 2; ++kk) {
            bf16x8 af[2], bfr[4];
#pragma unroll
            for (int m = 0; m < 2; ++m)
                af[m] = *(const bf16x8*)&sA[(wr * 32 + m * 16 + lr) * BK + kk * 32 + lg * 8];
#pragma unroll
            for (int n = 0; n < 4; ++n)
                bfr[n] = *(const bf16x8*)&sB[(wc * 64 + n * 16 + lr) * BK + kk * 32 + lg * 8];
#pragma unroll
            for (int m = 0; m < 2; ++m)
#pragma unroll
                for (int n = 0; n < 4; ++n)
                    acc[m][n] = MFMA16(af[m], bfr[n], acc[m][n]);
        }
    }

#pragma unroll
    for (int m = 0; m < 2; ++m) {
#pragma unroll
        for (int n = 0; n < 4; ++n) {
            const int r = row0 + wr * 32 + m * 16 + lg * 4;
            const int c = col0 + wc * 64 + n * 16 + lr;
            const float bv = bias[c];
            if constexpr (MODE == 0) {
                u16* C = (u16*)Cp;
#pragma unroll
                for (int j = 0; j < 4; ++j)
                    C[(size_t)(r + j) * N + c] = f2bf((acc[m][n][j] + bv) * alpha);
            } else {
                float* C = (float*)Cp;
#pragma unroll
                for (int j = 0; j < 4; ++j)
                    C[(size_t)(r + j) * N + c] =
                        (acc[m][n][j] + bv) * alpha + resid[(size_t)(r + j) * N + c];
            }
        }
    }
}

// ---------------------------------------------------------------------------
// Flash cross-attention, v6: occupancy play. v3 structure (8 waves = 2 kv
// groups x 4 q-waves of 16 q) but KVBLK=32 and 1KB P strips -> LDS 40KB and
// VGPR<=64 (launch_bounds(512,8)) -> 4 blocks/CU = 32 waves/CU (8/SIMD, HW
// max). Doubles iteration count but doubles TLP; VALU pipe saturates and
// drains/barriers overlap across 4 independent blocks.
// LDS: K dbuf [2][2grp][32x128B] 16K | V dbuf [2][2grp][64x64B] 16K | P 8K.
// V/P use 16B-chunk XOR swizzle keyed by (lr>>1)&3 (2-way = free).
// ---------------------------------------------------------------------------
__global__ __launch_bounds__(512, 8)
void attn_fwd(const u16* __restrict__ Q, const u16* __restrict__ Kg,
              const u16* __restrict__ Vt, u16* __restrict__ O)
{
    constexpr int D = 1024, CSTR = 19;
    __shared__ __align__(16) char smem[40960];

    const int tid = threadIdx.x, wid = tid >> 6, lane = tid & 63;
    const int grp = wid >> 2, w = wid & 3;
    const int lr = lane & 15, lg = lane >> 4;
    const int rs = lr & 7;              // K-read swizzle key (16B chunks of 8)
    const int vk = (lr >> 1) & 3;       // V/P swizzle key (16B chunks of 4)

    // XCD swizzle: 512 wgs, 64 consecutive work items per XCD
    const int fid = blockIdx.x;
    const int wkid = (fid & 7) * 64 + (fid >> 3);
    const int qblk = wkid & 15, h = (wkid >> 4) & 15, b = wkid >> 8;
    const int q0 = qblk * 64 + w * 16;

    // Q fragments (Q pre-scaled by 0.125*log2e in its GEMM)
    const u16* Qrow = Q + (size_t)(b * 1024 + q0 + lr) * D + h * 64;
    const bf16x8 qf0 = *(const bf16x8*)(Qrow + lg * 8);
    const bf16x8 qf1 = *(const bf16x8*)(Qrow + 32 + lg * 8);

    // K staging: wave stages 8 rows (srow) of its group's 32-row tile
    const int srow = w * 8 + (lane >> 3);
    const int scol = ((lane & 7) ^ (srow & 7)) * 8;
    const u16* kp = Kg + (size_t)(b * 4096 + grp * 2048 + srow) * D + h * 64 + scol;
    // V staging: wave stages 16 d-rows (vrow) x 64B of the group's V^T tile
    const int vrow = w * 16 + (lane >> 2);
    const int vcol = ((lane & 3) ^ ((vrow >> 1) & 3)) * 8;
    const u16* vp = Vt + ((size_t)(b * 16 + h) * 64 + vrow) * 4096 + grp * 2048 + vcol;

    char* sPw = smem + 32768 + wid * 1024;   // per-wave 16x64B P strip

    f32x4 po[4];
#pragma unroll
    for (int df = 0; df < 4; ++df) po[df] = (f32x4){0.f, 0.f, 0.f, 0.f};
    float m = -INFINITY, l = 0.f;

    auto stage = [&](int buf, int kv0) {
        gload_lds16(kp + (size_t)kv0 * D, smem + buf * 8192 + grp * 4096 + w * 1024);
        gload_lds16(vp + kv0, smem + 16384 + buf * 8192 + grp * 4096 + w * 1024);
    };

    auto step = [&](int t, int cur) {
        if (t < 63) stage(cur ^ 1, (t + 1) * 32);

        const u16* kb = (const u16*)(smem + cur * 8192 + grp * 4096);
        const u16* vb = (const u16*)(smem + 16384 + cur * 8192 + grp * 4096);

        // S^T[kv][q] = K . Q^T  (log2 domain), kv tile = 32 rows
        f32x4 s4[2];
#pragma unroll
        for (int f = 0; f < 2; ++f) {
            const int r = f * 16 + lr;
            bf16x8 k0v = *(const bf16x8*)&kb[r * 64 + (lg ^ rs) * 8];
            bf16x8 k1v = *(const bf16x8*)&kb[r * 64 + ((lg + 4) ^ rs) * 8];
            f32x4 z = (f32x4){0.f, 0.f, 0.f, 0.f};
            z = MFMA16(k0v, qf0, z);
            s4[f] = MFMA16(k1v, qf1, z);
        }

        // defer-max online softmax (base-2)
        float pmax = fmaxf(fmaxf(fmaxf(s4[0][0], s4[0][1]), fmaxf(s4[0][2], s4[0][3])),
                           fmaxf(fmaxf(s4[1][0], s4[1][1]), fmaxf(s4[1][2], s4[1][3])));
        if (!__all(pmax <= m)) {
            float tmax = fmaxf(pmax, __shfl_xor(pmax, 16, 64));
            tmax = fmaxf(tmax, __shfl_xor(tmax, 32, 64));
            const float mn = fmaxf(m, tmax);
            const float corr = fexp2(m - mn);
            l *= corr;
#pragma unroll
            for (int df = 0; df < 4; ++df) po[df] *= corr;
            m = mn;
        }
        float lsum = 0.f;
        uint2 pk[2];
#pragma unroll
        for (int f = 0; f < 2; ++f) {
            float p0 = fexp2(s4[f][0] - m);
            float p1 = fexp2(s4[f][1] - m);
            float p2 = fexp2(s4[f][2] - m);
            float p3 = fexp2(s4[f][3] - m);
            lsum += (p0 + p1) + (p2 + p3);
            pk[f].x = cvt_pk_bf16(p0, p1);
            pk[f].y = cvt_pk_bf16(p2, p3);
        }
        l += lsum;

        // P[q=lr][kv 16f+4lg..+4] -> strip, 16B-chunk swizzle ^vk
#pragma unroll
        for (int f = 0; f < 2; ++f)
            *(uint2*)(sPw + lr * 64 + ((2 * f + (lg >> 1)) ^ vk) * 16 + (lg & 1) * 8) = pk[f];

        // out^T[d][q] += V^T . P^T  (one 16x16x32 covers all 32 kv)
        bf16x8 pf = *(const bf16x8*)(sPw + lr * 64 + (lg ^ vk) * 16);
#pragma unroll
        for (int df = 0; df < 4; ++df) {
            const int r = df * 16 + lr;
            bf16x8 vf = *(const bf16x8*)&vb[r * 32 + (lg ^ vk) * 8];
            po[df] = MFMA16(vf, pf, po[df]);
        }

        asm volatile("s_waitcnt vmcnt(0)" ::: "memory");
        asm volatile("s_barrier" ::: "memory");
    };

    stage(0, 0);
    asm volatile("s_waitcnt vmcnt(0)" ::: "memory");
    asm volatile("s_barrier" ::: "memory");

    for (int tt = 0; tt < 32; ++tt) {
        step(tt * 2, 0);
        step(tt * 2 + 1, 1);
    }

    // reduce per-lane l across the q-column
    l += __shfl_xor(l, 16, 64);
    l += __shfl_xor(l, 32, 64);

    // merge the two kv halves through LDS (K/V regions dead now)
    float* cb = (float*)smem;
    if (grp == 1) {
        float* dst = cb + (size_t)(w * 64 + lane) * CSTR;
        dst[0] = m; dst[1] = l;
#pragma unroll
        for (int df = 0; df < 4; ++df)
#pragma unroll
            for (int j = 0; j < 4; ++j) dst[2 + df * 4 + j] = po[df][j];
    }
    __syncthreads();
    if (grp == 0) {
        const float* src = cb + (size_t)(w * 64 + lane) * CSTR;
        const float m1 = src[0], l1 = src[1];
        const float M = fmaxf(m, m1);
        const float c0 = fexp2(m - M), c1 = fexp2(m1 - M);
        const float rl = 1.f / (l * c0 + l1 * c1);
        u16* Orow = O + (size_t)(b * 1024 + q0 + lr) * D + h * 64;
#pragma unroll
        for (int df = 0; df < 4; ++df) {
            U16x4 opk = { f2bf((po[df][0] * c0 + src[2 + df * 4 + 0] * c1) * rl),
                          f2bf((po[df][1] * c0 + src[2 + df * 4 + 1] * c1) * rl),
                          f2bf((po[df][2] * c0 + src[2 + df * 4 + 2] * c1) * rl),
                          f2bf((po[df][3] * c0 + src[2 + df * 4 + 3] * c1) * rl) };
            *(U16x4*)&Orow[df * 16 + lg * 4] = opk;
        }
    }
}

// ---------------------------------------------------------------------------
extern "C" void kernel_launch(void* const* d_in, const int* in_sizes, int n_in,
                              void* d_out, int out_size, void* d_ws, size_t ws_size,
                              hipStream_t stream)
{
    const float* query   = (const float*)d_in[0];
    const float* context = (const float*)d_in[1];
    const float* wq = (const float*)d_in[2];
    const float* bq = (const float*)d_in[3];
    const float* wk = (const float*)d_in[4];
    const float* bk = (const float*)d_in[5];
    const float* wv = (const float*)d_in[6];
    const float* bv = (const float*)d_in[7];
    const float* wo = (const float*)d_in[8];
    const float* bo = (const float*)d_in[9];
    const float* g_q  = (const float*)d_in[10];
    const float* b_q  = (const float*)d_in[11];
    const float* g_kv = (const float*)d_in[12];
    const float* b_kv = (const float*)d_in[13];

    char* p = (char*)d_ws;
    auto alloc = [&](size_t bytes) { char* r = p; p += (bytes + 255) & ~(size_t)255; return r; };
    u16*   wqb  = (u16*)alloc(1024 * 1024 * 2);
    u16*   wkb  = (u16*)alloc(1024 * 1024 * 2);
    u16*   wvb  = (u16*)alloc(1024 * 1024 * 2);
    u16*   wob  = (u16*)alloc(1024 * 1024 * 2);
    float* qn32 = (float*)alloc((size_t)2048 * 1024 * 4);
    u16*   qnb  = (u16*)alloc((size_t)2048 * 1024 * 2);
    u16*   cnb  = (u16*)alloc((size_t)8192 * 1024 * 2);
    u16*   Qb   = (u16*)alloc((size_t)2048 * 1024 * 2);
    u16*   Kb   = (u16*)alloc((size_t)8192 * 1024 * 2);
    u16*   Vtb  = (u16*)alloc((size_t)8192 * 1024 * 2);
    u16*   AOb  = (u16*)alloc((size_t)2048 * 1024 * 2);

    prep<<<3584, 256, 0, stream>>>(query, context, g_q, b_q, g_kv, b_kv,
                                   qn32, qnb, cnb,
                                   (const float4*)wq, (const float4*)wk,
                                   (const float4*)wv, (const float4*)wo,
                                   (U16x4*)wqb, (U16x4*)wkb, (U16x4*)wvb, (U16x4*)wob);

    // Q = (qn.wq^T + bq) * 0.125 * log2(e)  (attn scale + exp2 conversion folded)
    gemm_bt64<0><<<dim3(32, 8), 256, 0, stream>>>(qnb, wqb, bq, nullptr, Qb, 2048, 1024, 1024, 0.18033688f);
    // K row-major + V transposed, one pass over cnb
    gemm_kv<<<dim3(64, 8), 512, 0, stream>>>(cnb, wkb, wvb, bk, bv, Kb, Vtb);

    attn_fwd<<<dim3(512), 512, 0, stream>>>(Qb, Kb, Vtb, AOb);

    // out = qn + AO.wo^T + bo   (f32 output, residual fused)
    gemm_bt64<1><<<dim3(32, 8), 256, 0, stream>>>(AOb, wob, bo, qn32, d_out, 2048, 1024, 1024, 1.0f);
}